// Round 3
// baseline (3764.260 us; speedup 1.0000x reference)
//
#include <hip/hip_runtime.h>
#include <hip/hip_bf16.h>

typedef unsigned short u16;
using bf16x8 = __attribute__((ext_vector_type(8))) short;
using f32x4  = __attribute__((ext_vector_type(4))) float;

#define NB   4
#define NT   90
#define NIMG 360
#define LL   240
#define DD   64
#define HID  512
#define NJ   2048
#define ST   512   // scan threads per block
#define SBLK 64    // scan blocks

#define DEV __device__ __forceinline__

DEV float bf2f(u16 x){ unsigned int u = ((unsigned int)x) << 16; float f; __builtin_memcpy(&f, &u, 4); return f; }
DEV u16 f2bf(float f){ unsigned int u; __builtin_memcpy(&u, &f, 4); unsigned int r = (u + 0x7FFFu + ((u >> 16) & 1u)) >> 16; return (u16)r; }
DEV float sigm(float x){ return 1.f / (1.f + __expf(-x)); }
DEV float tanh_f(float x){ x = fminf(fmaxf(x, -15.f), 15.f); float e = __expf(2.f*x); return (e - 1.f) / (e + 1.f); }

// ---------------- workspace layout (bytes) ----------------
static const size_t G_OFF     = 0;            // u16 [90][240][4][2048]  = 353,894,400 B
static const size_t CAMCL_OFF = 0;            // conv temporaries alias over G (dead before G written)
static const size_t A1_OFF    = 88473600;
static const size_t A2_OFF    = 154828800;
static const size_t A3_OFF    = 182476800;
static const size_t A4_OFF    = 190771200;
static const size_t A5_OFF    = 201830400;
static const size_t W1B_OFF   = 212889600;
static const size_t W2B_OFF   = 212903936;
static const size_t W3B_OFF   = 212968448;
static const size_t W4B_OFF   = 213075968;
static const size_t W5B_OFF   = 213137408;
static const size_t FEATS_OFF = 353894400;    // fp32 [360][240][64]
static const size_t PROJ_OFF  = 376012800;    // fp32 [360][240][64]
static const size_t WWT_OFF   = 398131200;    // fp32 [512][64]   w_w^T
static const size_t WHHP_OFF  = 398262272;    // bf16 [512][2048] whh^T, j-permuted
static const size_t BSUM_OFF  = 400359424;    // fp32 [2048] bih+bhh, j-permuted
static const size_t SW1T_OFF  = 400367616;    // fp32 [512][100]
static const size_t VW1T_OFF  = 400572416;    // fp32 [512][100]
static const size_t HX_OFF    = 400777216;    // fp32 [4][512] (8KB) ; +8192 alpha [4][240] ; +12288 barrier
static const size_t CX_OFF    = 400793600;    // (unused now)
static const size_t HSEQ_OFF  = 400809984;    // fp32 [90][4][512]
static const size_t WS_NEEDED = 401547264;

// ---------------- camera NCHW fp32 -> channels-last bf16 [n][h][w][8] ----------------
__global__ __launch_bounds__(256) void cam_to_cl(const float* __restrict__ cam, u16* __restrict__ out)
{
    int i = blockIdx.x * 256 + threadIdx.x;
    if (i >= NIMG * 96 * 160) return;
    int hw = i % (96 * 160);
    int n  = i / (96 * 160);
    const float* p = cam + (size_t)n * 3 * 96 * 160 + hw;
    bf16x8 v;
    v[0] = (short)f2bf(p[0]);
    v[1] = (short)f2bf(p[15360]);
    v[2] = (short)f2bf(p[30720]);
    v[3] = 0; v[4] = 0; v[5] = 0; v[6] = 0; v[7] = 0;
    *(bf16x8*)&out[(size_t)i * 8] = v;
}

// ---------------- weight prep for convs ----------------
__global__ __launch_bounds__(256) void prep_wbf(
    const float* __restrict__ w, u16* __restrict__ wbf,
    int COUT, int CIN, int CI_PAD, int KHW, int CELLS_PAD, int M_PAD)
{
    int K_PAD = CELLS_PAD * CI_PAD;
    int total = M_PAD * K_PAD;
    for (int i = blockIdx.x * 256 + threadIdx.x; i < total; i += gridDim.x * 256){
        int co = i / K_PAD, kk = i % K_PAD;
        int cell = kk / CI_PAD, ci = kk % CI_PAD;
        float v = 0.f;
        if (co < COUT && cell < KHW * KHW && ci < CIN){
            int kh = cell / KHW, kw = cell % KHW;
            v = w[((size_t)(co * CIN + ci) * KHW + kh) * KHW + kw];
        }
        wbf[i] = f2bf(v);
    }
}

// ---------------- implicit-GEMM MFMA conv (channels-last bf16 in/out) ----------------
template<int CI_PAD, int M_PAD, int COUT, int CO_STORE, int KHW, int CELLS_PAD,
         int S, int P, int HIN, int WIN, int HOUT, int WOUT, int TOH, int TOW>
__global__ __launch_bounds__(256) void conv_mfma(
    const u16* __restrict__ in, const u16* __restrict__ wbf,
    const float* __restrict__ bias, u16* __restrict__ out)
{
    constexpr int K_PAD = CELLS_PAD * CI_PAD;
    constexpr int CP8   = CI_PAD / 8;
    constexpr int TIH   = (TOH - 1) * S + KHW;
    constexpr int TIW   = (TOW - 1) * S + KHW;
    constexpr int TIW_H = (TIW + 1) / 2;
    constexpr int NF    = TOH * TOW / 16;
    constexpr int NK0   = K_PAD / 32;
    constexpr int MF    = M_PAD / 16;
    constexpr int NPW   = (NF + 3) / 4;
    constexpr int LDSE  = (S == 2) ? TIH * CP8 * 2 * TIW_H * 8 : TIH * CP8 * TIW * 8;
    static_assert((TOH * TOW) % 16 == 0, "N tile");
    static_assert(K_PAD % 32 == 0, "K pad");

    __shared__ u16 lds[LDSE];

    int tile = blockIdx.x, n = blockIdx.y;
    constexpr int TW_T = WOUT / TOW;
    int th = tile / TW_T, tw = tile % TW_T;
    int oh0 = th * TOH, ow0 = tw * TOW;
    int ih0 = oh0 * S - P, iw0 = ow0 * S - P;
    int tid = threadIdx.x;

    constexpr int CHUNKS = TIH * TIW * CP8;
    for (int i = tid; i < CHUNKS; i += 256){
        int c8 = i % CP8; int r2 = i / CP8;
        int iw = r2 % TIW, ih = r2 / TIW;
        int ihg = ih0 + ih, iwg = iw0 + iw;
        bf16x8 v = {0,0,0,0,0,0,0,0};
        if (ihg >= 0 && ihg < HIN && iwg >= 0 && iwg < WIN)
            v = *(const bf16x8*)&in[(((size_t)n * HIN + ihg) * WIN + iwg) * CI_PAD + c8 * 8];
        int off;
        if (S == 2) off = (((ih * CP8 + c8) * 2 + (iw & 1)) * TIW_H + (iw >> 1)) * 8;
        else        off = ((ih * CP8 + c8) * TIW + iw) * 8;
        *(bf16x8*)&lds[off] = v;
    }
    __syncthreads();

    int lane = tid & 63, wv = tid >> 6;
    int col = lane & 15, grp = lane >> 4;

    int ihb[NPW], iwb[NPW];
    bool act[NPW];
#pragma unroll
    for (int i2 = 0; i2 < NPW; i2++){
        int nf = wv + i2 * 4;
        act[i2] = (nf < NF);
        int nfc = act[i2] ? nf : 0;
        int nsp = nfc * 16 + col;
        ihb[i2] = (nsp / TOW) * S;
        iwb[i2] = (nsp % TOW) * S;
    }

    f32x4 acc[MF][NPW];
#pragma unroll
    for (int mf = 0; mf < MF; mf++)
#pragma unroll
        for (int i2 = 0; i2 < NPW; i2++)
            acc[mf][i2] = (f32x4){0.f, 0.f, 0.f, 0.f};

    for (int k0 = 0; k0 < NK0; k0++){
        bf16x8 a[MF];
#pragma unroll
        for (int mf = 0; mf < MF; mf++)
            a[mf] = *(const bf16x8*)&wbf[(size_t)(mf * 16 + col) * K_PAD + k0 * 32 + grp * 8];
        int k8 = k0 * 32 + grp * 8;
        int cell = k8 / CI_PAD;
        int ci0  = k8 - cell * CI_PAD;
        if (cell >= KHW * KHW) cell = 0;
        int kh = cell / KHW, kw = cell - (cell / KHW) * KHW;
        int cb = ci0 >> 3;
#pragma unroll
        for (int i2 = 0; i2 < NPW; i2++){
            if (!act[i2]) continue;
            int ih = ihb[i2] + kh;
            int off;
            if (S == 2) off = (((ih * CP8 + cb) * 2 + (kw & 1)) * TIW_H + (iwb[i2] >> 1) + (kw >> 1)) * 8;
            else        off = ((ih * CP8 + cb) * TIW + iwb[i2] + kw) * 8;
            bf16x8 b = *(const bf16x8*)&lds[off];
#pragma unroll
            for (int mf = 0; mf < MF; mf++)
                acc[mf][i2] = __builtin_amdgcn_mfma_f32_16x16x32_bf16(a[mf], b, acc[mf][i2], 0, 0, 0);
        }
    }

#pragma unroll
    for (int i2 = 0; i2 < NPW; i2++){
        if (!act[i2]) continue;
        int nf = wv + i2 * 4;
        int nsp = nf * 16 + col;
        int oh = oh0 + nsp / TOW, ow = ow0 + nsp % TOW;
        size_t obase = (((size_t)n * HOUT + oh) * WOUT + ow) * CO_STORE;
#pragma unroll
        for (int mf = 0; mf < MF; mf++){
            int cobase = mf * 16 + grp * 4;
#pragma unroll
            for (int r = 0; r < 4; r++){
                int co = cobase + r;
                if (co < CO_STORE){
                    float x = (co < COUT) ? fmaxf(acc[mf][i2][r] + bias[co], 0.f) : 0.f;
                    out[obase + co] = f2bf(x);
                }
            }
        }
    }
}

// ---------------- feats rearrange ----------------
__global__ __launch_bounds__(256) void extract_feats(const u16* __restrict__ a5, float* __restrict__ feats)
{
    int idx = blockIdx.x * 256 + threadIdx.x;
    if (idx >= NIMG * 12 * 20 * 64) return;
    int c = idx & 63; int t1 = idx >> 6;
    int w = t1 % 20; t1 /= 20;
    int h = t1 % 12; int n = t1 / 12;
    float v = bf2f(a5[idx]);
    int flat = w * 768 + c * 12 + h;
    int d = flat / 240, l = flat % 240;
    feats[((size_t)n * LL + l) * DD + d] = v;
}

// ---------------- proj = feats @ proj_w.T + proj_b ----------------
__global__ __launch_bounds__(256) void proj_kernel(
    const float* __restrict__ feats, const float* __restrict__ pw,
    const float* __restrict__ pb, float* __restrict__ proj)
{
    __shared__ float pws[64][65];
    __shared__ float fs[4][64];
    int tid = threadIdx.x;
    size_t R0 = (size_t)blockIdx.x * 4;
    for (int i = tid; i < 4096; i += 256){
        int dd = i / 64, d = i % 64;
        pws[d][dd] = pw[dd*64 + d];
    }
    { int r = tid / 64, d = tid % 64; fs[r][d] = feats[(R0 + r)*64 + d]; }
    __syncthreads();
    int r = tid / 64, dd = tid % 64;
    float a = pb[dd];
    for (int d = 0; d < 64; d++) a = fmaf(fs[r][d], pws[d][dd], a);
    proj[(R0 + r)*64 + dd] = a;
}

// ---------------- prep: transposes / permutes / bias combine ----------------
__global__ __launch_bounds__(256) void prep(
    const float* __restrict__ w_w, const float* __restrict__ whh,
    const float* __restrict__ bih, const float* __restrict__ bhh,
    const float* __restrict__ sw1, const float* __restrict__ vw1,
    float* __restrict__ w_wT, u16* __restrict__ whh_p, float* __restrict__ bsum,
    float* __restrict__ sw1T, float* __restrict__ vw1T)
{
    int idx = blockIdx.x * 256 + threadIdx.x;
    int stride = gridDim.x * 256;
    for (int i = idx; i < 512*64; i += stride){
        int k = i / 64, dd = i % 64;
        w_wT[i] = w_w[dd*512 + k];
    }
    for (int i = idx; i < 512*2048; i += stride){
        int k = i / 2048, jj = i % 2048;
        int u = jj >> 2, g = jj & 3, j = g*512 + u;
        whh_p[i] = f2bf(whh[(size_t)j*512 + k]);
    }
    for (int i = idx; i < 2048; i += stride){
        int u = i >> 2, g = i & 3, j = g*512 + u;
        bsum[i] = bih[j] + bhh[j];
    }
    for (int i = idx; i < 512*100; i += stride){
        int k = i / 100, u = i % 100;
        sw1T[i] = sw1[u*512 + k];
        vw1T[i] = vw1[u*512 + k];
    }
}

// ---------------- gcompute via MFMA ----------------
// Per l: C[m=360(pad384)][jj=2048] = feats[m][l][:64] . wih[j(jj)][l*64+:64]
// grid (8 jtiles, 240 l, 3 mtiles), 256 thr. Reg-staged fp32->bf16, XOR-swizzled LDS.
__global__ __launch_bounds__(256, 2) void gcompute_mfma(
    const float* __restrict__ feats, const float* __restrict__ wih, u16* __restrict__ G)
{
    __shared__ u16 Asw[128 * 64];      // [m][granule-slot] 16KB
    __shared__ u16 Bsw[256 * 64];      // [jj][granule-slot] 32KB
    __shared__ float obuf[4][16 * 64]; // per-wave epilogue bounce 16KB
    int jt = blockIdx.x, l = blockIdx.y, mt = blockIdx.z;
    int j0 = jt * 256, m0 = mt * 128;
    int tid = threadIdx.x;
    int g8 = tid & 7;

    // stage B: 256 rows of 64 f32 -> bf16 swizzled. 8 threads/row, 8 passes.
    for (int p = 0; p < 8; p++){
        int row = p * 32 + (tid >> 3);
        int jj = j0 + row;
        int j = (jj & 3) * 512 + (jj >> 2);
        const float* src = wih + (size_t)j * 15360 + l * 64 + g8 * 8;
        float4 v0 = *(const float4*)src;
        float4 v1 = *(const float4*)(src + 4);
        bf16x8 pk;
        pk[0]=(short)f2bf(v0.x); pk[1]=(short)f2bf(v0.y); pk[2]=(short)f2bf(v0.z); pk[3]=(short)f2bf(v0.w);
        pk[4]=(short)f2bf(v1.x); pk[5]=(short)f2bf(v1.y); pk[6]=(short)f2bf(v1.z); pk[7]=(short)f2bf(v1.w);
        *(bf16x8*)&Bsw[(row * 8 + (g8 ^ (row & 7))) * 8] = pk;
    }
    // stage A: 128 rows (m0..m0+127; rows>=360 read junk, stores guarded)
    for (int p = 0; p < 4; p++){
        int row = p * 32 + (tid >> 3);
        const float* src = feats + ((size_t)(m0 + row) * LL + l) * DD + g8 * 8;
        float4 v0 = *(const float4*)src;
        float4 v1 = *(const float4*)(src + 4);
        bf16x8 pk;
        pk[0]=(short)f2bf(v0.x); pk[1]=(short)f2bf(v0.y); pk[2]=(short)f2bf(v0.z); pk[3]=(short)f2bf(v0.w);
        pk[4]=(short)f2bf(v1.x); pk[5]=(short)f2bf(v1.y); pk[6]=(short)f2bf(v1.z); pk[7]=(short)f2bf(v1.w);
        *(bf16x8*)&Asw[(row * 8 + (g8 ^ (row & 7))) * 8] = pk;
    }
    __syncthreads();

    int lane = tid & 63, w = tid >> 6;
    int col = lane & 15, grp = lane >> 4;

    f32x4 acc[8][4];
#pragma unroll
    for (int mf = 0; mf < 8; mf++)
#pragma unroll
        for (int nf = 0; nf < 4; nf++) acc[mf][nf] = (f32x4){0.f,0.f,0.f,0.f};

#pragma unroll
    for (int k0 = 0; k0 < 2; k0++){
        int gg = k0 * 4 + grp;
        bf16x8 bfr[4];
#pragma unroll
        for (int nf = 0; nf < 4; nf++){
            int row = w * 64 + nf * 16 + col;
            bfr[nf] = *(const bf16x8*)&Bsw[(row * 8 + (gg ^ (row & 7))) * 8];
        }
#pragma unroll
        for (int mf = 0; mf < 8; mf++){
            int row = mf * 16 + col;
            bf16x8 a = *(const bf16x8*)&Asw[(row * 8 + (gg ^ (row & 7))) * 8];
#pragma unroll
            for (int nf = 0; nf < 4; nf++)
                acc[mf][nf] = __builtin_amdgcn_mfma_f32_16x16x32_bf16(a, bfr[nf], acc[mf][nf], 0, 0, 0);
        }
    }
    __syncthreads();

    // epilogue: bounce each 16x64 m-block through LDS, store bf16x8 rows
#pragma unroll
    for (int mf = 0; mf < 8; mf++){
#pragma unroll
        for (int nf = 0; nf < 4; nf++)
#pragma unroll
            for (int r = 0; r < 4; r++)
                obuf[w][(grp * 4 + r) * 64 + nf * 16 + col] = acc[mf][nf][r];
#pragma unroll
        for (int p = 0; p < 2; p++){
            int rloc = p * 8 + (lane >> 3);
            int c0 = (lane & 7) * 8;
            float4 r0 = *(const float4*)&obuf[w][rloc * 64 + c0];
            float4 r1 = *(const float4*)&obuf[w][rloc * 64 + c0 + 4];
            int m = m0 + mf * 16 + rloc;
            if (m < NIMG){
                int b = m / NT, tt = m % NT;
                bf16x8 pk;
                pk[0]=(short)f2bf(r0.x); pk[1]=(short)f2bf(r0.y); pk[2]=(short)f2bf(r0.z); pk[3]=(short)f2bf(r0.w);
                pk[4]=(short)f2bf(r1.x); pk[5]=(short)f2bf(r1.y); pk[6]=(short)f2bf(r1.z); pk[7]=(short)f2bf(r1.w);
                *(bf16x8*)&G[(((size_t)tt * LL + l) * NB + b) * NJ + j0 + w * 64 + c0] = pk;
            }
        }
        __syncthreads();
    }
}

// ---------------- persistent scan ----------------
DEV void gbar(unsigned int* bar, unsigned int target)
{
    __syncthreads();
    if (threadIdx.x == 0){
        __threadfence();
        __hip_atomic_fetch_add(bar, 1u, __ATOMIC_ACQ_REL, __HIP_MEMORY_SCOPE_AGENT);
        int guard = 0;
        while (__hip_atomic_load(bar, __ATOMIC_RELAXED, __HIP_MEMORY_SCOPE_AGENT) < target){
            if (++guard > 40000000) break;
            __builtin_amdgcn_s_sleep(2);
        }
        __threadfence();
    }
    __syncthreads();
}

DEV void attn_block(int b, int tstep,
                    const float* __restrict__ proj, const float* __restrict__ w_wT,
                    const float* __restrict__ w_b, const float* __restrict__ waw,
                    const float* __restrict__ wab, const float* __restrict__ hx,
                    float* __restrict__ alpha_g, float* aux, float* apjs, float* esL)
{
    int tid = threadIdx.x;
    for (int i = tid; i < HID; i += ST) aux[i] = hx[b * HID + i];
    __syncthreads();
    {
        int dd = tid >> 3, dq = tid & 7;
        float p = 0.f;
        for (int ki = 0; ki < 64; ki++){
            int k = dq * 64 + ki;
            p = fmaf(aux[k], w_wT[k * 64 + dd], p);
        }
        p += __shfl_xor(p, 1); p += __shfl_xor(p, 2); p += __shfl_xor(p, 4);
        if (dq == 0) apjs[dd] = p + w_b[dd];
    }
    __syncthreads();
    if (tid < LL){
        const float4* pr = (const float4*)(proj + ((size_t)(b * NT + tstep) * LL + tid) * DD);
        float e = 0.f;
#pragma unroll
        for (int d4 = 0; d4 < 16; d4++){
            float4 v = pr[d4];
            e = fmaf(tanh_f(v.x + apjs[d4*4+0]), waw[d4*4+0], e);
            e = fmaf(tanh_f(v.y + apjs[d4*4+1]), waw[d4*4+1], e);
            e = fmaf(tanh_f(v.z + apjs[d4*4+2]), waw[d4*4+2], e);
            e = fmaf(tanh_f(v.w + apjs[d4*4+3]), waw[d4*4+3], e);
        }
        esL[tid] = e + wab[0];
    }
    __syncthreads();
    if (tid < 64){
        float m = -1e30f;
        for (int l = tid; l < LL; l += 64) m = fmaxf(m, esL[l]);
#pragma unroll
        for (int off = 32; off; off >>= 1) m = fmaxf(m, __shfl_xor(m, off));
        float ex[4]; int c = 0;
        float ssum = 0.f;
        for (int l = tid; l < LL; l += 64){ float e2 = __expf(esL[l] - m); ex[c++] = e2; ssum += e2; }
#pragma unroll
        for (int off = 32; off; off >>= 1) ssum += __shfl_xor(ssum, off);
        float inv = 1.f / ssum;
        c = 0;
        for (int l = tid; l < LL; l += 64) alpha_g[b * LL + l] = ex[c++] * inv;
    }
}

DEV void warm_g(const u16* __restrict__ G, int tnext, int jj0)
{
    const u16* Gt = G + (size_t)tnext * (LL * NB * NJ);
    float acc = 0.f;
#pragma unroll
    for (int r = 0; r < 8; r++){
        int idx = threadIdx.x + r * ST;
        if (idx < 3840){
            int c = idx >> 2, wq = idx & 3;
            int l = c >> 2, b2 = c & 3;
            float4 v = *(const float4*)&Gt[((size_t)(l * NB + b2)) * NJ + jj0 + wq * 8];
            acc += v.x + v.y + v.z + v.w;
        }
    }
    asm volatile("" :: "v"(acc));
}

DEV void warm_proj(const float* __restrict__ proj, int b, int tnext)
{
    const float4* p = (const float4*)(proj + ((size_t)(b * NT + tnext)) * LL * DD);
    float acc = 0.f;
#pragma unroll
    for (int r = 0; r < 8; r++){
        int idx = threadIdx.x + r * ST;
        if (idx < 3840){
            float4 v = p[idx];
            acc += v.x + v.y + v.z + v.w;
        }
    }
    asm volatile("" :: "v"(acc));
}

__global__ __launch_bounds__(ST) void scan_kernel(
    const float* __restrict__ proj, const u16* __restrict__ G,
    const float* __restrict__ w_wT, const float* __restrict__ w_b,
    const float* __restrict__ waw, const float* __restrict__ wab,
    const u16* __restrict__ whh_p, const float* __restrict__ bsum,
    float* __restrict__ hx, float* __restrict__ alpha_g,
    unsigned int* __restrict__ bar, float* __restrict__ hseq)
{
    __shared__ float hxs[NB][HID];   // 8KB
    __shared__ float als[NB][LL];    // 3.75KB
    __shared__ float red[16][NB][32];// 8KB
    __shared__ float aux[512];       // 2KB (attn hx stage / gates result)
    __shared__ float apjs[DD];

    int tid = threadIdx.x;
    int blk = blockIdx.x;
    int s = ((blk & 31) << 1) | (blk >> 5);   // XCD-paired jj-span mapping
    int jj0 = s * 32;
    unsigned int gen = 0;

    int jjq = tid & 7, gb = (tid >> 3) & 3, kq = tid >> 5;
    int ob = tid >> 3, oul = tid & 7;  // owner decode (tid<32)
    float creg = 0.f;

    if (blk < NB)
        attn_block(blk, 0, proj, w_wT, w_b, waw, wab, hx, alpha_g, aux, apjs, (float*)red);
    gen++; gbar(bar, gen * SBLK);

    for (int t = 0; t < NT; t++){
        for (int i = tid; i < NB * HID; i += ST) hxs[i >> 9][i & 511] = hx[i];
        for (int i = tid; i < NB * LL; i += ST) als[i / LL][i % LL] = alpha_g[i];
        __syncthreads();

        float ac0 = 0.f, ac1 = 0.f, ac2 = 0.f, ac3 = 0.f;
        {
            const u16* gp = G + (size_t)t * (LL * NB * NJ)
                          + ((size_t)(kq * 15 * NB + gb)) * NJ + jj0 + (jjq << 2);
            for (int li = 0; li < 15; li++){
                short4 gv = *(const short4*)gp;
                float al = als[gb][kq * 15 + li];
                ac0 = fmaf(al, bf2f((u16)gv.x), ac0);
                ac1 = fmaf(al, bf2f((u16)gv.y), ac1);
                ac2 = fmaf(al, bf2f((u16)gv.z), ac2);
                ac3 = fmaf(al, bf2f((u16)gv.w), ac3);
                gp += NB * NJ;
            }
            const u16* wp = whh_p + (size_t)(kq * 32) * NJ + jj0 + (jjq << 2);
            for (int ki = 0; ki < 32; ki++){
                short4 wv = *(const short4*)wp;
                float h = hxs[gb][kq * 32 + ki];
                ac0 = fmaf(h, bf2f((u16)wv.x), ac0);
                ac1 = fmaf(h, bf2f((u16)wv.y), ac1);
                ac2 = fmaf(h, bf2f((u16)wv.z), ac2);
                ac3 = fmaf(h, bf2f((u16)wv.w), ac3);
                wp += NJ;
            }
        }
        red[kq][gb][(jjq << 2) + 0] = ac0;
        red[kq][gb][(jjq << 2) + 1] = ac1;
        red[kq][gb][(jjq << 2) + 2] = ac2;
        red[kq][gb][(jjq << 2) + 3] = ac3;
        __syncthreads();
        if (tid < 128){
            int b = tid >> 5, jl = tid & 31;
            float g2 = bsum[jj0 + jl];
#pragma unroll
            for (int q = 0; q < 16; q++) g2 += red[q][b][jl];
            aux[(b << 5) + jl] = g2;
        }
        __syncthreads();
        if (tid < 32){
            float gi = aux[(ob << 5) + (oul << 2) + 0];
            float gf = aux[(ob << 5) + (oul << 2) + 1];
            float gg = aux[(ob << 5) + (oul << 2) + 2];
            float go = aux[(ob << 5) + (oul << 2) + 3];
            creg = sigm(gf) * creg + sigm(gi) * tanhf(gg);
            float h = sigm(go) * tanhf(creg);
            int u = (s << 3) + oul;
            hx[ob * HID + u] = h;
            hseq[((size_t)t * NB + ob) * HID + u] = h;
        }
        if (t == NT - 1) break;
        gen++; gbar(bar, gen * SBLK);
        if (blk < NB)
            attn_block(blk, t + 1, proj, w_wT, w_b, waw, wab, hx, alpha_g, aux, apjs, (float*)red);
        else if (blk >= 32 && blk < 32 + NB)
            warm_proj(proj, blk - 32, t + 1);
        else
            warm_g(G, t + 1, jj0);
        gen++; gbar(bar, gen * SBLK);
    }
}

// ---------------- MLP heads ----------------
__global__ __launch_bounds__(256) void mlp_kernel(
    const float* __restrict__ hseq,
    const float* __restrict__ sw1T, const float* __restrict__ sb1,
    const float* __restrict__ sw2,  const float* __restrict__ sb2,
    const float* __restrict__ sw3,  const float* __restrict__ sb3,
    const float* __restrict__ sw4,  const float* __restrict__ sb4,
    const float* __restrict__ vw1T, const float* __restrict__ vb1,
    const float* __restrict__ vw2,  const float* __restrict__ vb2,
    const float* __restrict__ vw3,  const float* __restrict__ vb3,
    const float* __restrict__ vw4,  const float* __restrict__ vb4,
    float* __restrict__ out)
{
    __shared__ float h0[HID];
    __shared__ float h1[2][100];
    __shared__ float h2[2][52];
    __shared__ float h3[2][12];
    int tb = blockIdx.x;
    int tid = threadIdx.x;
    for (int i = tid; i < HID; i += 256) h0[i] = hseq[(size_t)tb * HID + i];
    __syncthreads();
    if (tid < 100){
        float a = sb1[tid];
        for (int k = 0; k < HID; k++) a = fmaf(h0[k], sw1T[k*100 + tid], a);
        h1[0][tid] = fmaxf(a, 0.f);
    } else if (tid >= 128 && tid < 228){
        int u = tid - 128;
        float a = vb1[u];
        for (int k = 0; k < HID; k++) a = fmaf(h0[k], vw1T[k*100 + u], a);
        h1[1][u] = fmaxf(a, 0.f);
    }
    __syncthreads();
    if (tid < 50){
        float a = sb2[tid];
        for (int k = 0; k < 100; k++) a = fmaf(h1[0][k], sw2[tid*100 + k], a);
        h2[0][tid] = fmaxf(a, 0.f);
    } else if (tid >= 128 && tid < 178){
        int u = tid - 128;
        float a = vb2[u];
        for (int k = 0; k < 100; k++) a = fmaf(h1[1][k], vw2[u*100 + k], a);
        h2[1][u] = fmaxf(a, 0.f);
    }
    __syncthreads();
    if (tid < 10){
        float a = sb3[tid];
        for (int k = 0; k < 50; k++) a = fmaf(h2[0][k], sw3[tid*50 + k], a);
        h3[0][tid] = fmaxf(a, 0.f);
    } else if (tid >= 128 && tid < 138){
        int u = tid - 128;
        float a = vb3[u];
        for (int k = 0; k < 50; k++) a = fmaf(h2[1][k], vw3[u*50 + k], a);
        h3[1][u] = fmaxf(a, 0.f);
    }
    __syncthreads();
    if (tid == 0){
        float a = sb4[0];
        for (int k = 0; k < 10; k++) a = fmaf(h3[0][k], sw4[k], a);
        out[tb] = a;
    } else if (tid == 128){
        float a = vb4[0];
        for (int k = 0; k < 10; k++) a = fmaf(h3[1][k], vw4[k], a);
        out[360 + tb] = a;
    }
}

extern "C" void kernel_launch(void* const* d_in, const int* in_sizes, int n_in,
                              void* d_out, int out_size, void* d_ws, size_t ws_size,
                              hipStream_t stream)
{
    (void)in_sizes; (void)n_in; (void)out_size;
    if (ws_size < WS_NEEDED) return;

    const float* cam   = (const float*)d_in[0];
    const float* cw1   = (const float*)d_in[1];  const float* cb1 = (const float*)d_in[2];
    const float* cw2   = (const float*)d_in[3];  const float* cb2 = (const float*)d_in[4];
    const float* cw3   = (const float*)d_in[5];  const float* cb3 = (const float*)d_in[6];
    const float* cw4   = (const float*)d_in[7];  const float* cb4 = (const float*)d_in[8];
    const float* cw5   = (const float*)d_in[9];  const float* cb5 = (const float*)d_in[10];
    const float* pw    = (const float*)d_in[11]; const float* pb  = (const float*)d_in[12];
    const float* w_w   = (const float*)d_in[13]; const float* w_b = (const float*)d_in[14];
    const float* waw   = (const float*)d_in[15]; const float* wab = (const float*)d_in[16];
    const float* wih   = (const float*)d_in[17]; const float* whh = (const float*)d_in[18];
    const float* bih   = (const float*)d_in[19]; const float* bhh = (const float*)d_in[20];
    const float* sw1   = (const float*)d_in[21]; const float* sb1 = (const float*)d_in[22];
    const float* sw2   = (const float*)d_in[23]; const float* sb2 = (const float*)d_in[24];
    const float* sw3   = (const float*)d_in[25]; const float* sb3 = (const float*)d_in[26];
    const float* sw4   = (const float*)d_in[27]; const float* sb4 = (const float*)d_in[28];
    const float* vw1   = (const float*)d_in[29]; const float* vb1 = (const float*)d_in[30];
    const float* vw2   = (const float*)d_in[31]; const float* vb2 = (const float*)d_in[32];
    const float* vw3   = (const float*)d_in[33]; const float* vb3 = (const float*)d_in[34];
    const float* vw4   = (const float*)d_in[35]; const float* vb4 = (const float*)d_in[36];

    char* ws = (char*)d_ws;
    u16*   camcl = (u16*)(ws + CAMCL_OFF);
    u16*   a1    = (u16*)(ws + A1_OFF);
    u16*   a2    = (u16*)(ws + A2_OFF);
    u16*   a3    = (u16*)(ws + A3_OFF);
    u16*   a4    = (u16*)(ws + A4_OFF);
    u16*   a5    = (u16*)(ws + A5_OFF);
    u16*   w1b   = (u16*)(ws + W1B_OFF);
    u16*   w2b   = (u16*)(ws + W2B_OFF);
    u16*   w3b   = (u16*)(ws + W3B_OFF);
    u16*   w4b   = (u16*)(ws + W4B_OFF);
    u16*   w5b   = (u16*)(ws + W5B_OFF);
    float* feats = (float*)(ws + FEATS_OFF);
    float* proj  = (float*)(ws + PROJ_OFF);
    float* w_wT  = (float*)(ws + WWT_OFF);
    u16*   whh_p = (u16*)  (ws + WHHP_OFF);
    float* bsum  = (float*)(ws + BSUM_OFF);
    float* sw1T  = (float*)(ws + SW1T_OFF);
    float* vw1T  = (float*)(ws + VW1T_OFF);
    float* hx    = (float*)(ws + HX_OFF);
    float* alpha = (float*)(ws + HX_OFF + 8192);
    unsigned int* bar = (unsigned int*)(ws + HX_OFF + 12288);
    float* hseq  = (float*)(ws + HSEQ_OFF);
    u16*   G     = (u16*)  (ws + G_OFF);

    cam_to_cl<<<(NIMG*96*160 + 255)/256, 256, 0, stream>>>(cam, camcl);
    prep_wbf<<<64, 256, 0, stream>>>(cw1, w1b, 24,  3,  8, 5, 28, 32);
    prep_wbf<<<64, 256, 0, stream>>>(cw2, w2b, 36, 24, 24, 5, 28, 48);
    prep_wbf<<<64, 256, 0, stream>>>(cw3, w3b, 48, 36, 40, 5, 28, 48);
    prep_wbf<<<64, 256, 0, stream>>>(cw4, w4b, 64, 48, 48, 3, 10, 64);
    prep_wbf<<<64, 256, 0, stream>>>(cw5, w5b, 64, 64, 64, 3,  9, 64);

    conv_mfma<   8,    32,   24,  24,   5,  28,   2, 2, 96, 160, 48, 80,  8, 40>
        <<<dim3(12, NIMG), 256, 0, stream>>>(camcl, w1b, cb1, a1);
    conv_mfma<  24,    48,   36,  40,   5,  28,   2, 2, 48,  80, 24, 40,  8, 20>
        <<<dim3(6, NIMG), 256, 0, stream>>>(a1, w2b, cb2, a2);
    conv_mfma<  40,    48,   48,  48,   5,  28,   2, 2, 24,  40, 12, 20, 12, 20>
        <<<dim3(1, NIMG), 256, 0, stream>>>(a2, w3b, cb3, a3);
    conv_mfma<  48,    64,   64,  64,   3,  10,   1, 1, 12,  20, 12, 20, 12, 20>
        <<<dim3(1, NIMG), 256, 0, stream>>>(a3, w4b, cb4, a4);
    conv_mfma<  64,    64,   64,  64,   3,   9,   1, 1, 12,  20, 12, 20, 12, 20>
        <<<dim3(1, NIMG), 256, 0, stream>>>(a4, w5b, cb5, a5);

    extract_feats<<<(NIMG*12*20*64 + 255)/256, 256, 0, stream>>>(a5, feats);
    proj_kernel<<<NIMG*LL/4, 256, 0, stream>>>(feats, pw, pb, proj);
    prep<<<2048, 256, 0, stream>>>(w_w, whh, bih, bhh, sw1, vw1, w_wT, whh_p, bsum, sw1T, vw1T);
    gcompute_mfma<<<dim3(8, 240, 3), 256, 0, stream>>>(feats, wih, G);

    hipMemsetAsync(ws + HX_OFF, 0, 32768, stream);  // hx, alpha, barrier

    scan_kernel<<<SBLK, ST, 0, stream>>>(proj, G, w_wT, w_b, waw, wab, whh_p, bsum,
                                         hx, alpha, bar, hseq);

    mlp_kernel<<<360, 256, 0, stream>>>(hseq,
        sw1T, sb1, sw2, sb2, sw3, sb3, sw4, sb4,
        vw1T, vb1, vw2, vb2, vw3, vb3, vw4, vb4, (float*)d_out);
}

// Round 4
// 2439.771 us; speedup vs baseline: 1.5429x; 1.5429x over previous
//
#include <hip/hip_runtime.h>
#include <hip/hip_bf16.h>

typedef unsigned short u16;
using bf16x8 = __attribute__((ext_vector_type(8))) short;
using f32x4  = __attribute__((ext_vector_type(4))) float;

#define NB   4
#define NT   90
#define NIMG 360
#define LL   240
#define DD   64
#define HID  512
#define NJ   2048

#define DEV __device__ __forceinline__

DEV float bf2f(u16 x){ unsigned int u = ((unsigned int)x) << 16; float f; __builtin_memcpy(&f, &u, 4); return f; }
DEV u16 f2bf(float f){ unsigned int u; __builtin_memcpy(&u, &f, 4); unsigned int r = (u + 0x7FFFu + ((u >> 16) & 1u)) >> 16; return (u16)r; }
DEV float sigm(float x){ return 1.f / (1.f + __expf(-x)); }
DEV float tanh_f(float x){ x = fminf(fmaxf(x, -15.f), 15.f); float e = __expf(2.f*x); return (e - 1.f) / (e + 1.f); }

// ---------------- workspace layout (bytes) ----------------
static const size_t G_OFF     = 0;            // u16 [90][240][4][2048]  = 353,894,400 B
static const size_t CAMCL_OFF = 0;            // conv temporaries alias over G (dead before G written)
static const size_t A1_OFF    = 88473600;
static const size_t A2_OFF    = 154828800;
static const size_t A3_OFF    = 182476800;
static const size_t A4_OFF    = 190771200;
static const size_t A5_OFF    = 201830400;
static const size_t W1B_OFF   = 212889600;
static const size_t W2B_OFF   = 212903936;
static const size_t W3B_OFF   = 212968448;
static const size_t W4B_OFF   = 213075968;
static const size_t W5B_OFF   = 213137408;
static const size_t FEATS_OFF = 353894400;    // fp32 [360][240][64]
static const size_t PROJ_OFF  = 376012800;    // fp32 [360][240][64]
static const size_t WWT_OFF   = 398131200;    // fp32 [512][64]   w_w^T
static const size_t WHHP_OFF  = 398262272;    // bf16 [512][2048] whh^T, j-permuted
static const size_t BSUM_OFF  = 400359424;    // fp32 [2048] bih+bhh, j-permuted
static const size_t SW1T_OFF  = 400367616;    // fp32 [512][100] (written AFTER scan by prep2)
static const size_t PART_OFF  = 400367616;    // fp32 [4][4][2048] = 128KB, aliases sw1T during scan
static const size_t VW1T_OFF  = 400572416;    // fp32 [512][100]
static const size_t HX_OFF    = 400777216;    // fp32 [4][512] = 8KB
static const size_t ALPHA_OFF = 400785408;    // fp32 [4][240] (4KB slot)
static const size_t CXN_OFF   = 400789504;    // fp32 [4][512] = 8KB
static const size_t HSEQ_OFF  = 400809984;    // fp32 [90][4][512]
static const size_t WS_NEEDED = 401547264;

// ---------------- camera NCHW fp32 -> channels-last bf16 [n][h][w][8] ----------------
__global__ __launch_bounds__(256) void cam_to_cl(const float* __restrict__ cam, u16* __restrict__ out)
{
    int i = blockIdx.x * 256 + threadIdx.x;
    if (i >= NIMG * 96 * 160) return;
    int hw = i % (96 * 160);
    int n  = i / (96 * 160);
    const float* p = cam + (size_t)n * 3 * 96 * 160 + hw;
    bf16x8 v;
    v[0] = (short)f2bf(p[0]);
    v[1] = (short)f2bf(p[15360]);
    v[2] = (short)f2bf(p[30720]);
    v[3] = 0; v[4] = 0; v[5] = 0; v[6] = 0; v[7] = 0;
    *(bf16x8*)&out[(size_t)i * 8] = v;
}

// ---------------- weight prep for convs ----------------
__global__ __launch_bounds__(256) void prep_wbf(
    const float* __restrict__ w, u16* __restrict__ wbf,
    int COUT, int CIN, int CI_PAD, int KHW, int CELLS_PAD, int M_PAD)
{
    int K_PAD = CELLS_PAD * CI_PAD;
    int total = M_PAD * K_PAD;
    for (int i = blockIdx.x * 256 + threadIdx.x; i < total; i += gridDim.x * 256){
        int co = i / K_PAD, kk = i % K_PAD;
        int cell = kk / CI_PAD, ci = kk % CI_PAD;
        float v = 0.f;
        if (co < COUT && cell < KHW * KHW && ci < CIN){
            int kh = cell / KHW, kw = cell % KHW;
            v = w[((size_t)(co * CIN + ci) * KHW + kh) * KHW + kw];
        }
        wbf[i] = f2bf(v);
    }
}

// ---------------- implicit-GEMM MFMA conv (channels-last bf16 in/out) ----------------
template<int CI_PAD, int M_PAD, int COUT, int CO_STORE, int KHW, int CELLS_PAD,
         int S, int P, int HIN, int WIN, int HOUT, int WOUT, int TOH, int TOW>
__global__ __launch_bounds__(256) void conv_mfma(
    const u16* __restrict__ in, const u16* __restrict__ wbf,
    const float* __restrict__ bias, u16* __restrict__ out)
{
    constexpr int K_PAD = CELLS_PAD * CI_PAD;
    constexpr int CP8   = CI_PAD / 8;
    constexpr int TIH   = (TOH - 1) * S + KHW;
    constexpr int TIW   = (TOW - 1) * S + KHW;
    constexpr int TIW_H = (TIW + 1) / 2;
    constexpr int NF    = TOH * TOW / 16;
    constexpr int NK0   = K_PAD / 32;
    constexpr int MF    = M_PAD / 16;
    constexpr int NPW   = (NF + 3) / 4;
    constexpr int LDSE  = (S == 2) ? TIH * CP8 * 2 * TIW_H * 8 : TIH * CP8 * TIW * 8;
    static_assert((TOH * TOW) % 16 == 0, "N tile");
    static_assert(K_PAD % 32 == 0, "K pad");

    __shared__ u16 lds[LDSE];

    int tile = blockIdx.x, n = blockIdx.y;
    constexpr int TW_T = WOUT / TOW;
    int th = tile / TW_T, tw = tile % TW_T;
    int oh0 = th * TOH, ow0 = tw * TOW;
    int ih0 = oh0 * S - P, iw0 = ow0 * S - P;
    int tid = threadIdx.x;

    constexpr int CHUNKS = TIH * TIW * CP8;
    for (int i = tid; i < CHUNKS; i += 256){
        int c8 = i % CP8; int r2 = i / CP8;
        int iw = r2 % TIW, ih = r2 / TIW;
        int ihg = ih0 + ih, iwg = iw0 + iw;
        bf16x8 v = {0,0,0,0,0,0,0,0};
        if (ihg >= 0 && ihg < HIN && iwg >= 0 && iwg < WIN)
            v = *(const bf16x8*)&in[(((size_t)n * HIN + ihg) * WIN + iwg) * CI_PAD + c8 * 8];
        int off;
        if (S == 2) off = (((ih * CP8 + c8) * 2 + (iw & 1)) * TIW_H + (iw >> 1)) * 8;
        else        off = ((ih * CP8 + c8) * TIW + iw) * 8;
        *(bf16x8*)&lds[off] = v;
    }
    __syncthreads();

    int lane = tid & 63, wv = tid >> 6;
    int col = lane & 15, grp = lane >> 4;

    int ihb[NPW], iwb[NPW];
    bool act[NPW];
#pragma unroll
    for (int i2 = 0; i2 < NPW; i2++){
        int nf = wv + i2 * 4;
        act[i2] = (nf < NF);
        int nfc = act[i2] ? nf : 0;
        int nsp = nfc * 16 + col;
        ihb[i2] = (nsp / TOW) * S;
        iwb[i2] = (nsp % TOW) * S;
    }

    f32x4 acc[MF][NPW];
#pragma unroll
    for (int mf = 0; mf < MF; mf++)
#pragma unroll
        for (int i2 = 0; i2 < NPW; i2++)
            acc[mf][i2] = (f32x4){0.f, 0.f, 0.f, 0.f};

    for (int k0 = 0; k0 < NK0; k0++){
        bf16x8 a[MF];
#pragma unroll
        for (int mf = 0; mf < MF; mf++)
            a[mf] = *(const bf16x8*)&wbf[(size_t)(mf * 16 + col) * K_PAD + k0 * 32 + grp * 8];
        int k8 = k0 * 32 + grp * 8;
        int cell = k8 / CI_PAD;
        int ci0  = k8 - cell * CI_PAD;
        if (cell >= KHW * KHW) cell = 0;
        int kh = cell / KHW, kw = cell - (cell / KHW) * KHW;
        int cb = ci0 >> 3;
#pragma unroll
        for (int i2 = 0; i2 < NPW; i2++){
            if (!act[i2]) continue;
            int ih = ihb[i2] + kh;
            int off;
            if (S == 2) off = (((ih * CP8 + cb) * 2 + (kw & 1)) * TIW_H + (iwb[i2] >> 1) + (kw >> 1)) * 8;
            else        off = ((ih * CP8 + cb) * TIW + iwb[i2] + kw) * 8;
            bf16x8 b = *(const bf16x8*)&lds[off];
#pragma unroll
            for (int mf = 0; mf < MF; mf++)
                acc[mf][i2] = __builtin_amdgcn_mfma_f32_16x16x32_bf16(a[mf], b, acc[mf][i2], 0, 0, 0);
        }
    }

#pragma unroll
    for (int i2 = 0; i2 < NPW; i2++){
        if (!act[i2]) continue;
        int nf = wv + i2 * 4;
        int nsp = nf * 16 + col;
        int oh = oh0 + nsp / TOW, ow = ow0 + nsp % TOW;
        size_t obase = (((size_t)n * HOUT + oh) * WOUT + ow) * CO_STORE;
#pragma unroll
        for (int mf = 0; mf < MF; mf++){
            int cobase = mf * 16 + grp * 4;
#pragma unroll
            for (int r = 0; r < 4; r++){
                int co = cobase + r;
                if (co < CO_STORE){
                    float x = (co < COUT) ? fmaxf(acc[mf][i2][r] + bias[co], 0.f) : 0.f;
                    out[obase + co] = f2bf(x);
                }
            }
        }
    }
}

// ---------------- feats rearrange ----------------
__global__ __launch_bounds__(256) void extract_feats(const u16* __restrict__ a5, float* __restrict__ feats)
{
    int idx = blockIdx.x * 256 + threadIdx.x;
    if (idx >= NIMG * 12 * 20 * 64) return;
    int c = idx & 63; int t1 = idx >> 6;
    int w = t1 % 20; t1 /= 20;
    int h = t1 % 12; int n = t1 / 12;
    float v = bf2f(a5[idx]);
    int flat = w * 768 + c * 12 + h;
    int d = flat / 240, l = flat % 240;
    feats[((size_t)n * LL + l) * DD + d] = v;
}

// ---------------- proj = feats @ proj_w.T + proj_b ----------------
__global__ __launch_bounds__(256) void proj_kernel(
    const float* __restrict__ feats, const float* __restrict__ pw,
    const float* __restrict__ pb, float* __restrict__ proj)
{
    __shared__ float pws[64][65];
    __shared__ float fs[4][64];
    int tid = threadIdx.x;
    size_t R0 = (size_t)blockIdx.x * 4;
    for (int i = tid; i < 4096; i += 256){
        int dd = i / 64, d = i % 64;
        pws[d][dd] = pw[dd*64 + d];
    }
    { int r = tid / 64, d = tid % 64; fs[r][d] = feats[(R0 + r)*64 + d]; }
    __syncthreads();
    int r = tid / 64, dd = tid % 64;
    float a = pb[dd];
    for (int d = 0; d < 64; d++) a = fmaf(fs[r][d], pws[d][dd], a);
    proj[(R0 + r)*64 + dd] = a;
}

// ---------------- prep: whh permute, bias combine, w_w transpose ----------------
__global__ __launch_bounds__(256) void prep(
    const float* __restrict__ w_w, const float* __restrict__ whh,
    const float* __restrict__ bih, const float* __restrict__ bhh,
    float* __restrict__ w_wT, u16* __restrict__ whh_p, float* __restrict__ bsum)
{
    int idx = blockIdx.x * 256 + threadIdx.x;
    int stride = gridDim.x * 256;
    for (int i = idx; i < 512*64; i += stride){
        int k = i / 64, dd = i % 64;
        w_wT[i] = w_w[dd*512 + k];
    }
    for (int i = idx; i < 512*2048; i += stride){
        int k = i / 2048, jj = i % 2048;
        int u = jj >> 2, g = jj & 3, j = g*512 + u;
        whh_p[i] = f2bf(whh[(size_t)j*512 + k]);
    }
    for (int i = idx; i < 2048; i += stride){
        int u = i >> 2, g = i & 3, j = g*512 + u;
        bsum[i] = bih[j] + bhh[j];
    }
}

// ---------------- prep2: MLP first-layer transposes (runs AFTER scan; sw1T aliases part) --------
__global__ __launch_bounds__(256) void prep2(
    const float* __restrict__ sw1, const float* __restrict__ vw1,
    float* __restrict__ sw1T, float* __restrict__ vw1T)
{
    int idx = blockIdx.x * 256 + threadIdx.x;
    int stride = gridDim.x * 256;
    for (int i = idx; i < 512*100; i += stride){
        int k = i / 100, u = i % 100;
        sw1T[i] = sw1[u*512 + k];
        vw1T[i] = vw1[u*512 + k];
    }
}

// ---------------- gcompute via MFMA ----------------
__global__ __launch_bounds__(256, 2) void gcompute_mfma(
    const float* __restrict__ feats, const float* __restrict__ wih, u16* __restrict__ G)
{
    __shared__ u16 Asw[128 * 64];
    __shared__ u16 Bsw[256 * 64];
    __shared__ float obuf[4][16 * 64];
    int jt = blockIdx.x, l = blockIdx.y, mt = blockIdx.z;
    int j0 = jt * 256, m0 = mt * 128;
    int tid = threadIdx.x;
    int g8 = tid & 7;

    for (int p = 0; p < 8; p++){
        int row = p * 32 + (tid >> 3);
        int jj = j0 + row;
        int j = (jj & 3) * 512 + (jj >> 2);
        const float* src = wih + (size_t)j * 15360 + l * 64 + g8 * 8;
        float4 v0 = *(const float4*)src;
        float4 v1 = *(const float4*)(src + 4);
        bf16x8 pk;
        pk[0]=(short)f2bf(v0.x); pk[1]=(short)f2bf(v0.y); pk[2]=(short)f2bf(v0.z); pk[3]=(short)f2bf(v0.w);
        pk[4]=(short)f2bf(v1.x); pk[5]=(short)f2bf(v1.y); pk[6]=(short)f2bf(v1.z); pk[7]=(short)f2bf(v1.w);
        *(bf16x8*)&Bsw[(row * 8 + (g8 ^ (row & 7))) * 8] = pk;
    }
    for (int p = 0; p < 4; p++){
        int row = p * 32 + (tid >> 3);
        const float* src = feats + ((size_t)(m0 + row) * LL + l) * DD + g8 * 8;
        float4 v0 = *(const float4*)src;
        float4 v1 = *(const float4*)(src + 4);
        bf16x8 pk;
        pk[0]=(short)f2bf(v0.x); pk[1]=(short)f2bf(v0.y); pk[2]=(short)f2bf(v0.z); pk[3]=(short)f2bf(v0.w);
        pk[4]=(short)f2bf(v1.x); pk[5]=(short)f2bf(v1.y); pk[6]=(short)f2bf(v1.z); pk[7]=(short)f2bf(v1.w);
        *(bf16x8*)&Asw[(row * 8 + (g8 ^ (row & 7))) * 8] = pk;
    }
    __syncthreads();

    int lane = tid & 63, w = tid >> 6;
    int col = lane & 15, grp = lane >> 4;

    f32x4 acc[8][4];
#pragma unroll
    for (int mf = 0; mf < 8; mf++)
#pragma unroll
        for (int nf = 0; nf < 4; nf++) acc[mf][nf] = (f32x4){0.f,0.f,0.f,0.f};

#pragma unroll
    for (int k0 = 0; k0 < 2; k0++){
        int gg = k0 * 4 + grp;
        bf16x8 bfr[4];
#pragma unroll
        for (int nf = 0; nf < 4; nf++){
            int row = w * 64 + nf * 16 + col;
            bfr[nf] = *(const bf16x8*)&Bsw[(row * 8 + (gg ^ (row & 7))) * 8];
        }
#pragma unroll
        for (int mf = 0; mf < 8; mf++){
            int row = mf * 16 + col;
            bf16x8 a = *(const bf16x8*)&Asw[(row * 8 + (gg ^ (row & 7))) * 8];
#pragma unroll
            for (int nf = 0; nf < 4; nf++)
                acc[mf][nf] = __builtin_amdgcn_mfma_f32_16x16x32_bf16(a, bfr[nf], acc[mf][nf], 0, 0, 0);
        }
    }
    __syncthreads();

#pragma unroll
    for (int mf = 0; mf < 8; mf++){
#pragma unroll
        for (int nf = 0; nf < 4; nf++)
#pragma unroll
            for (int r = 0; r < 4; r++)
                obuf[w][(grp * 4 + r) * 64 + nf * 16 + col] = acc[mf][nf][r];
#pragma unroll
        for (int p = 0; p < 2; p++){
            int rloc = p * 8 + (lane >> 3);
            int c0 = (lane & 7) * 8;
            float4 r0 = *(const float4*)&obuf[w][rloc * 64 + c0];
            float4 r1 = *(const float4*)&obuf[w][rloc * 64 + c0 + 4];
            int m = m0 + mf * 16 + rloc;
            if (m < NIMG){
                int b = m / NT, tt = m % NT;
                bf16x8 pk;
                pk[0]=(short)f2bf(r0.x); pk[1]=(short)f2bf(r0.y); pk[2]=(short)f2bf(r0.z); pk[3]=(short)f2bf(r0.w);
                pk[4]=(short)f2bf(r1.x); pk[5]=(short)f2bf(r1.y); pk[6]=(short)f2bf(r1.z); pk[7]=(short)f2bf(r1.w);
                *(bf16x8*)&G[(((size_t)tt * LL + l) * NB + b) * NJ + j0 + w * 64 + c0] = pk;
            }
        }
        __syncthreads();
    }
}

// ---------------- K1: gates partial (256 blocks = 64 jj-spans x 4 l/k-quarters) ----------------
__global__ __launch_bounds__(256) void gates_part_kernel(
    int t, const u16* __restrict__ G, const u16* __restrict__ whh_p,
    const float* __restrict__ hx, const float* __restrict__ alpha_g,
    float* __restrict__ part)
{
    __shared__ float als[NB][60];
    __shared__ float hxq[NB][128];
    __shared__ float red[8][NB][32];
    int s  = blockIdx.x;   // jj-span: jj in [s*32, s*32+32)
    int lq = blockIdx.y;   // l-quarter (60 l's) and k-quarter (128 k's)
    int jj0 = s * 32;
    int tid = threadIdx.x;

    for (int i = tid; i < NB * 60; i += 256){
        int b2 = i / 60, il = i % 60;
        als[b2][il] = alpha_g[b2 * LL + lq * 60 + il];
    }
    for (int i = tid; i < NB * 128; i += 256){
        int b2 = i >> 7, kk = i & 127;
        hxq[b2][kk] = hx[b2 * HID + lq * 128 + kk];
    }
    __syncthreads();

    int jjq = tid & 7, b = (tid >> 3) & 3, lg = tid >> 5;
    float ac0 = 0.f, ac1 = 0.f, ac2 = 0.f, ac3 = 0.f;

    const u16* gbase = G + (size_t)t * (LL * NB * NJ) + (size_t)b * NJ + jj0 + (jjq << 2);
    for (int i = lg; i < 60; i += 8){
        int l = lq * 60 + i;
        short4 gv = *(const short4*)(gbase + (size_t)l * NB * NJ);
        float al = als[b][i];
        ac0 = fmaf(al, bf2f((u16)gv.x), ac0);
        ac1 = fmaf(al, bf2f((u16)gv.y), ac1);
        ac2 = fmaf(al, bf2f((u16)gv.z), ac2);
        ac3 = fmaf(al, bf2f((u16)gv.w), ac3);
    }
    const u16* wbase = whh_p + (size_t)(lq * 128 + lg * 16) * NJ + jj0 + (jjq << 2);
#pragma unroll
    for (int ki = 0; ki < 16; ki++){
        short4 wv = *(const short4*)(wbase + (size_t)ki * NJ);
        float h = hxq[b][lg * 16 + ki];
        ac0 = fmaf(h, bf2f((u16)wv.x), ac0);
        ac1 = fmaf(h, bf2f((u16)wv.y), ac1);
        ac2 = fmaf(h, bf2f((u16)wv.z), ac2);
        ac3 = fmaf(h, bf2f((u16)wv.w), ac3);
    }
    red[lg][b][(jjq << 2) + 0] = ac0;
    red[lg][b][(jjq << 2) + 1] = ac1;
    red[lg][b][(jjq << 2) + 2] = ac2;
    red[lg][b][(jjq << 2) + 3] = ac3;
    __syncthreads();

    if (tid < 128){
        int b2 = tid >> 5, jl = tid & 31;
        float v = 0.f;
#pragma unroll
        for (int q = 0; q < 8; q++) v += red[q][b2][jl];
        part[((size_t)lq * NB + b2) * NJ + jj0 + jl] = v;
    }
}

// ---------------- K2: pointwise LSTM cell + attention for next step ----------------
// MODE 0: init (attention for t=0 only, hx=0). MODE 1: pointwise(t) + attention(t+1). MODE 2: pointwise(t) only.
template<int MODE>
__global__ __launch_bounds__(512) void cell_attn_kernel(
    int t, const float* __restrict__ part, const float* __restrict__ bsum,
    float* __restrict__ cx, float* __restrict__ hx_g, float* __restrict__ hseq,
    const float* __restrict__ proj, const float* __restrict__ w_wT,
    const float* __restrict__ w_b, const float* __restrict__ waw, const float* __restrict__ wab,
    float* __restrict__ alpha_g)
{
    __shared__ float hxs[HID];
    __shared__ float apjs[DD];
    __shared__ float esL[LL];
    int b = blockIdx.x, tid = threadIdx.x;

    if (MODE == 0){
        hxs[tid] = 0.f;
    } else {
        int u = tid;
        float4 p0 = *(const float4*)&part[((size_t)0 * NB + b) * NJ + u * 4];
        float4 p1 = *(const float4*)&part[((size_t)1 * NB + b) * NJ + u * 4];
        float4 p2 = *(const float4*)&part[((size_t)2 * NB + b) * NJ + u * 4];
        float4 p3 = *(const float4*)&part[((size_t)3 * NB + b) * NJ + u * 4];
        float4 bs = *(const float4*)&bsum[u * 4];
        float gi = p0.x + p1.x + p2.x + p3.x + bs.x;
        float gf = p0.y + p1.y + p2.y + p3.y + bs.y;
        float gg = p0.z + p1.z + p2.z + p3.z + bs.z;
        float go = p0.w + p1.w + p2.w + p3.w + bs.w;
        float c = sigm(gf) * cx[b * HID + u] + sigm(gi) * tanhf(gg);
        cx[b * HID + u] = c;
        float h = sigm(go) * tanhf(c);
        hxs[u] = h;
        hx_g[b * HID + u] = h;
        hseq[((size_t)t * NB + b) * HID + u] = h;
    }
    __syncthreads();
    if (MODE == 2) return;

    int tn = (MODE == 0) ? 0 : t + 1;

    // apj[dd] = sum_k hxs[k] * w_wT[k][dd] + w_b[dd]   (8 threads per dd)
    {
        int dd = tid >> 3, dq = tid & 7;
        float p = 0.f;
        for (int ki = 0; ki < 64; ki++){
            int k = dq * 64 + ki;
            p = fmaf(hxs[k], w_wT[k * 64 + dd], p);
        }
        p += __shfl_xor(p, 1); p += __shfl_xor(p, 2); p += __shfl_xor(p, 4);
        if (dq == 0) apjs[dd] = p + w_b[dd];
    }
    __syncthreads();

    // es[l] (2 threads per l, d-halves)
    if (tid < 480){
        int l = tid >> 1, dh = tid & 1;
        const float4* pr = (const float4*)(proj + ((size_t)(b * NT + tn) * LL + l) * DD + dh * 32);
        float e = 0.f;
#pragma unroll
        for (int d4 = 0; d4 < 8; d4++){
            float4 v = pr[d4];
            int d0 = dh * 32 + d4 * 4;
            e = fmaf(tanh_f(v.x + apjs[d0+0]), waw[d0+0], e);
            e = fmaf(tanh_f(v.y + apjs[d0+1]), waw[d0+1], e);
            e = fmaf(tanh_f(v.z + apjs[d0+2]), waw[d0+2], e);
            e = fmaf(tanh_f(v.w + apjs[d0+3]), waw[d0+3], e);
        }
        e += __shfl_xor(e, 1);
        if (dh == 0) esL[l] = e + wab[0];
    }
    __syncthreads();

    // softmax over l
    if (tid < 64){
        float m = -1e30f;
        for (int l = tid; l < LL; l += 64) m = fmaxf(m, esL[l]);
#pragma unroll
        for (int off = 32; off; off >>= 1) m = fmaxf(m, __shfl_xor(m, off));
        float ex[4]; int c = 0;
        float ssum = 0.f;
        for (int l = tid; l < LL; l += 64){ float e2 = __expf(esL[l] - m); ex[c++] = e2; ssum += e2; }
#pragma unroll
        for (int off = 32; off; off >>= 1) ssum += __shfl_xor(ssum, off);
        float inv = 1.f / ssum;
        c = 0;
        for (int l = tid; l < LL; l += 64) alpha_g[b * LL + l] = ex[c++] * inv;
    }
}

// ---------------- MLP heads ----------------
__global__ __launch_bounds__(256) void mlp_kernel(
    const float* __restrict__ hseq,
    const float* __restrict__ sw1T, const float* __restrict__ sb1,
    const float* __restrict__ sw2,  const float* __restrict__ sb2,
    const float* __restrict__ sw3,  const float* __restrict__ sb3,
    const float* __restrict__ sw4,  const float* __restrict__ sb4,
    const float* __restrict__ vw1T, const float* __restrict__ vb1,
    const float* __restrict__ vw2,  const float* __restrict__ vb2,
    const float* __restrict__ vw3,  const float* __restrict__ vb3,
    const float* __restrict__ vw4,  const float* __restrict__ vb4,
    float* __restrict__ out)
{
    __shared__ float h0[HID];
    __shared__ float h1[2][100];
    __shared__ float h2[2][52];
    __shared__ float h3[2][12];
    int tb = blockIdx.x;
    int tid = threadIdx.x;
    for (int i = tid; i < HID; i += 256) h0[i] = hseq[(size_t)tb * HID + i];
    __syncthreads();
    if (tid < 100){
        float a = sb1[tid];
        for (int k = 0; k < HID; k++) a = fmaf(h0[k], sw1T[k*100 + tid], a);
        h1[0][tid] = fmaxf(a, 0.f);
    } else if (tid >= 128 && tid < 228){
        int u = tid - 128;
        float a = vb1[u];
        for (int k = 0; k < HID; k++) a = fmaf(h0[k], vw1T[k*100 + u], a);
        h1[1][u] = fmaxf(a, 0.f);
    }
    __syncthreads();
    if (tid < 50){
        float a = sb2[tid];
        for (int k = 0; k < 100; k++) a = fmaf(h1[0][k], sw2[tid*100 + k], a);
        h2[0][tid] = fmaxf(a, 0.f);
    } else if (tid >= 128 && tid < 178){
        int u = tid - 128;
        float a = vb2[u];
        for (int k = 0; k < 100; k++) a = fmaf(h1[1][k], vw2[u*100 + k], a);
        h2[1][u] = fmaxf(a, 0.f);
    }
    __syncthreads();
    if (tid < 10){
        float a = sb3[tid];
        for (int k = 0; k < 50; k++) a = fmaf(h2[0][k], sw3[tid*50 + k], a);
        h3[0][tid] = fmaxf(a, 0.f);
    } else if (tid >= 128 && tid < 138){
        int u = tid - 128;
        float a = vb3[u];
        for (int k = 0; k < 50; k++) a = fmaf(h2[1][k], vw3[u*50 + k], a);
        h3[1][u] = fmaxf(a, 0.f);
    }
    __syncthreads();
    if (tid == 0){
        float a = sb4[0];
        for (int k = 0; k < 10; k++) a = fmaf(h3[0][k], sw4[k], a);
        out[tb] = a;
    } else if (tid == 128){
        float a = vb4[0];
        for (int k = 0; k < 10; k++) a = fmaf(h3[1][k], vw4[k], a);
        out[360 + tb] = a;
    }
}

extern "C" void kernel_launch(void* const* d_in, const int* in_sizes, int n_in,
                              void* d_out, int out_size, void* d_ws, size_t ws_size,
                              hipStream_t stream)
{
    (void)in_sizes; (void)n_in; (void)out_size;
    if (ws_size < WS_NEEDED) return;

    const float* cam   = (const float*)d_in[0];
    const float* cw1   = (const float*)d_in[1];  const float* cb1 = (const float*)d_in[2];
    const float* cw2   = (const float*)d_in[3];  const float* cb2 = (const float*)d_in[4];
    const float* cw3   = (const float*)d_in[5];  const float* cb3 = (const float*)d_in[6];
    const float* cw4   = (const float*)d_in[7];  const float* cb4 = (const float*)d_in[8];
    const float* cw5   = (const float*)d_in[9];  const float* cb5 = (const float*)d_in[10];
    const float* pw    = (const float*)d_in[11]; const float* pb  = (const float*)d_in[12];
    const float* w_w   = (const float*)d_in[13]; const float* w_b = (const float*)d_in[14];
    const float* waw   = (const float*)d_in[15]; const float* wab = (const float*)d_in[16];
    const float* wih   = (const float*)d_in[17]; const float* whh = (const float*)d_in[18];
    const float* bih   = (const float*)d_in[19]; const float* bhh = (const float*)d_in[20];
    const float* sw1   = (const float*)d_in[21]; const float* sb1 = (const float*)d_in[22];
    const float* sw2   = (const float*)d_in[23]; const float* sb2 = (const float*)d_in[24];
    const float* sw3   = (const float*)d_in[25]; const float* sb3 = (const float*)d_in[26];
    const float* sw4   = (const float*)d_in[27]; const float* sb4 = (const float*)d_in[28];
    const float* vw1   = (const float*)d_in[29]; const float* vb1 = (const float*)d_in[30];
    const float* vw2   = (const float*)d_in[31]; const float* vb2 = (const float*)d_in[32];
    const float* vw3   = (const float*)d_in[33]; const float* vb3 = (const float*)d_in[34];
    const float* vw4   = (const float*)d_in[35]; const float* vb4 = (const float*)d_in[36];

    char* ws = (char*)d_ws;
    u16*   camcl = (u16*)(ws + CAMCL_OFF);
    u16*   a1    = (u16*)(ws + A1_OFF);
    u16*   a2    = (u16*)(ws + A2_OFF);
    u16*   a3    = (u16*)(ws + A3_OFF);
    u16*   a4    = (u16*)(ws + A4_OFF);
    u16*   a5    = (u16*)(ws + A5_OFF);
    u16*   w1b   = (u16*)(ws + W1B_OFF);
    u16*   w2b   = (u16*)(ws + W2B_OFF);
    u16*   w3b   = (u16*)(ws + W3B_OFF);
    u16*   w4b   = (u16*)(ws + W4B_OFF);
    u16*   w5b   = (u16*)(ws + W5B_OFF);
    float* feats = (float*)(ws + FEATS_OFF);
    float* proj  = (float*)(ws + PROJ_OFF);
    float* w_wT  = (float*)(ws + WWT_OFF);
    u16*   whh_p = (u16*)  (ws + WHHP_OFF);
    float* bsum  = (float*)(ws + BSUM_OFF);
    float* part  = (float*)(ws + PART_OFF);
    float* sw1T  = (float*)(ws + SW1T_OFF);
    float* vw1T  = (float*)(ws + VW1T_OFF);
    float* hx    = (float*)(ws + HX_OFF);
    float* alpha = (float*)(ws + ALPHA_OFF);
    float* cx    = (float*)(ws + CXN_OFF);
    float* hseq  = (float*)(ws + HSEQ_OFF);
    u16*   G     = (u16*)  (ws + G_OFF);

    cam_to_cl<<<(NIMG*96*160 + 255)/256, 256, 0, stream>>>(cam, camcl);
    prep_wbf<<<64, 256, 0, stream>>>(cw1, w1b, 24,  3,  8, 5, 28, 32);
    prep_wbf<<<64, 256, 0, stream>>>(cw2, w2b, 36, 24, 24, 5, 28, 48);
    prep_wbf<<<64, 256, 0, stream>>>(cw3, w3b, 48, 36, 40, 5, 28, 48);
    prep_wbf<<<64, 256, 0, stream>>>(cw4, w4b, 64, 48, 48, 3, 10, 64);
    prep_wbf<<<64, 256, 0, stream>>>(cw5, w5b, 64, 64, 64, 3,  9, 64);

    conv_mfma<   8,    32,   24,  24,   5,  28,   2, 2, 96, 160, 48, 80,  8, 40>
        <<<dim3(12, NIMG), 256, 0, stream>>>(camcl, w1b, cb1, a1);
    conv_mfma<  24,    48,   36,  40,   5,  28,   2, 2, 48,  80, 24, 40,  8, 20>
        <<<dim3(6, NIMG), 256, 0, stream>>>(a1, w2b, cb2, a2);
    conv_mfma<  40,    48,   48,  48,   5,  28,   2, 2, 24,  40, 12, 20, 12, 20>
        <<<dim3(1, NIMG), 256, 0, stream>>>(a2, w3b, cb3, a3);
    conv_mfma<  48,    64,   64,  64,   3,  10,   1, 1, 12,  20, 12, 20, 12, 20>
        <<<dim3(1, NIMG), 256, 0, stream>>>(a3, w4b, cb4, a4);
    conv_mfma<  64,    64,   64,  64,   3,   9,   1, 1, 12,  20, 12, 20, 12, 20>
        <<<dim3(1, NIMG), 256, 0, stream>>>(a4, w5b, cb5, a5);

    extract_feats<<<(NIMG*12*20*64 + 255)/256, 256, 0, stream>>>(a5, feats);
    proj_kernel<<<NIMG*LL/4, 256, 0, stream>>>(feats, pw, pb, proj);
    prep<<<1024, 256, 0, stream>>>(w_w, whh, bih, bhh, w_wT, whh_p, bsum);
    gcompute_mfma<<<dim3(8, 240, 3), 256, 0, stream>>>(feats, wih, G);

    hipMemsetAsync(ws + HX_OFF, 0, 12288, stream);   // hx + alpha
    hipMemsetAsync(ws + CXN_OFF, 0, 8192, stream);   // cx

    // alpha[0]
    cell_attn_kernel<0><<<4, 512, 0, stream>>>(-1, part, bsum, cx, hx, hseq,
        proj, w_wT, w_b, waw, wab, alpha);

    for (int t = 0; t < NT; t++){
        gates_part_kernel<<<dim3(64, 4), 256, 0, stream>>>(t, G, whh_p, hx, alpha, part);
        if (t < NT - 1)
            cell_attn_kernel<1><<<4, 512, 0, stream>>>(t, part, bsum, cx, hx, hseq,
                proj, w_wT, w_b, waw, wab, alpha);
        else
            cell_attn_kernel<2><<<4, 512, 0, stream>>>(t, part, bsum, cx, hx, hseq,
                proj, w_wT, w_b, waw, wab, alpha);
    }

    prep2<<<256, 256, 0, stream>>>(sw1, vw1, sw1T, vw1T);

    mlp_kernel<<<360, 256, 0, stream>>>(hseq,
        sw1T, sb1, sw2, sb2, sw3, sb3, sw4, sb4,
        vw1T, vb1, vw2, vb2, vw3, vb3, vw4, vb4, (float*)d_out);
}